// Round 2
// baseline (109.254 us; speedup 1.0000x reference)
//
#include <hip/hip_runtime.h>
#include <hip/hip_cooperative_groups.h>

namespace cg = cooperative_groups;

// Problem: N=4096 rows, F=256 features, H=4 heads.
// Softmax identity: softmax_j(s_i[i,h] + s_j[j,h] + b[h]) == softmax_j(s_j[j,h])
// => attention weights independent of i; output is ONE length-F vector broadcast
// to all N rows:
//   v[f] = (1/H) * sum_h ( sum_j exp(s_j[j,h]) * x[j,f] ) / ( sum_j exp(s_j[j,h]) )
//   out[i,f] = leaky_relu(v[f], 0.2)
//
// This revision: single cooperative kernel (1 dispatch instead of 2).
// Phase A = per-block partials (identical math to previous k1_part),
// grid-wide sync, Phase B = reduce partials from L2 + broadcast-write output
// (identical math to previous k2_out). No atomics, no memset.

#define NROWS 4096
#define FDIM  256
#define HH    4
#define RPB   32            // rows per block
#define NB    (NROWS / RPB) // 128 blocks (all co-resident: 38KB LDS, 256 CUs)
#define PADF  260           // padded row stride: 1040B, 16B-aligned, 4-bank shift/row

// ws layout: u_part[NB][HH][FDIM] (512 KB), then z_part[NB][HH] (2 KB).

__global__ __launch_bounds__(256) void k_fused(const float* __restrict__ x,
                                               const float* __restrict__ W,
                                               float* __restrict__ u_part,
                                               float* __restrict__ z_part,
                                               float* __restrict__ out) {
    __shared__ __align__(16) float x_lds[RPB * PADF];   // 33.3 KB (reused in phase B)
    __shared__ __align__(16) float w_lds[HH * PADF];    // 4.2 KB
    __shared__ __align__(16) float e_lds[RPB * HH];

    const int t = threadIdx.x;
    const int b = blockIdx.x;
    const int row0 = b * RPB;

    // ---------------- Phase A: per-block partials ----------------

    // Stage W2 (= W[:, F:2F], row stride 2F=512 floats) as [h][c], padded.
    {
        int h = t >> 6, c4 = t & 63;
        float4 wv = ((const float4*)W)[(size_t)h * (2 * FDIM / 4) + (FDIM / 4) + c4];
        *(float4*)&w_lds[h * PADF + c4 * 4] = wv;
    }
    // Stage 32 x-rows: 2048 float4 -> 8 per thread, coalesced.
    for (int i = t; i < RPB * (FDIM / 4); i += 256) {
        int r = i >> 6, c4 = i & 63;
        float4 v = ((const float4*)x)[(size_t)(row0 + r) * (FDIM / 4) + c4];
        *(float4*)&x_lds[r * PADF + c4 * 4] = v;
    }
    __syncthreads();

    // Scores: thread -> (row r, head h, half); 128-feature half-dot via float4
    // LDS reads, pair-reduce via shfl_xor(1). Bank aliasing <=2-way (free).
    {
        int r = t >> 3, h = (t >> 1) & 3, half = t & 1;
        const float4* xr = (const float4*)&x_lds[r * PADF];
        const float4* wr = (const float4*)&w_lds[h * PADF];
        float acc = 0.f;
        #pragma unroll
        for (int i = 0; i < 32; ++i) {
            float4 a = xr[half * 32 + i];
            float4 w = wr[half * 32 + i];
            acc = fmaf(a.x, w.x, acc); acc = fmaf(a.y, w.y, acc);
            acc = fmaf(a.z, w.z, acc); acc = fmaf(a.w, w.w, acc);
        }
        acc += __shfl_xor(acc, 1);
        if (half == 0) e_lds[r * 4 + h] = __expf(acc);  // |s| < ~3: no max-shift needed
    }
    __syncthreads();

    // Per-block softmax-denominator partials.
    if (t < HH) {
        float z = 0.f;
        #pragma unroll
        for (int r = 0; r < RPB; ++r) z += e_lds[r * 4 + t];
        z_part[b * HH + t] = z;
    }

    // Per-block partial of u[h][f] = sum_j e[h,j]*x[j,f];  f = t.
    {
        float a0 = 0.f, a1 = 0.f, a2 = 0.f, a3 = 0.f;
        #pragma unroll 8
        for (int r = 0; r < RPB; ++r) {
            float xv = x_lds[r * PADF + t];
            float4 e4 = *(const float4*)&e_lds[r * 4];   // same addr all lanes: broadcast
            a0 = fmaf(e4.x, xv, a0);
            a1 = fmaf(e4.y, xv, a1);
            a2 = fmaf(e4.z, xv, a2);
            a3 = fmaf(e4.w, xv, a3);
        }
        float* up = u_part + (size_t)b * (HH * FDIM);
        up[0 * FDIM + t] = a0;
        up[1 * FDIM + t] = a1;
        up[2 * FDIM + t] = a2;
        up[3 * FDIM + t] = a3;
    }

    // ---------------- grid-wide sync ----------------
    __threadfence();            // device-scope visibility of partials
    cg::this_grid().sync();

    // ---------------- Phase B: reduce + broadcast write ----------------
    // Reuse x_lds: [0..255]=v, [256..767]=z staging, [768..771]=z finals.
    float* v_lds = x_lds;
    float* zl    = x_lds + FDIM;
    float* zf    = x_lds + FDIM + NB * HH;

    zl[t]       = z_part[t];
    zl[t + 256] = z_part[t + 256];
    __syncthreads();
    if (t < HH) {
        float z = 0.f;
        for (int bb = 0; bb < NB; ++bb) z += zl[bb * 4 + t];
        zf[t] = z;
    }

    // Reduce u partials: thread t owns column f=t for all 4 heads.
    // 512 KB per block from L2 (64 MiB aggregate), coalesced; hides zf latency.
    float a0 = 0.f, a1 = 0.f, a2 = 0.f, a3 = 0.f;
    for (int bb = 0; bb < NB; ++bb) {
        const float* up = u_part + (size_t)bb * (HH * FDIM);
        a0 += up[0 * FDIM + t];
        a1 += up[1 * FDIM + t];
        a2 += up[2 * FDIM + t];
        a3 += up[3 * FDIM + t];
    }
    __syncthreads();   // zf ready
    float val = 0.25f * (a0 / zf[0] + a1 / zf[1] + a2 / zf[2] + a3 / zf[3]);
    v_lds[t] = val > 0.f ? val : 0.2f * val;
    __syncthreads();

    // Broadcast-write this block's 32 rows (coalesced float4).
    const int c4 = t & 63;          // float4 column 0..63
    const int sub = t >> 6;         // 0..3, each handles 8 rows
    float4 v4 = *(const float4*)&v_lds[c4 * 4];
    float4* out4 = (float4*)out;
    #pragma unroll
    for (int k = 0; k < RPB / 4; ++k)
        out4[(size_t)(row0 + sub * (RPB / 4) + k) * (FDIM / 4) + c4] = v4;
}

extern "C" void kernel_launch(void* const* d_in, const int* in_sizes, int n_in,
                              void* d_out, int out_size, void* d_ws, size_t ws_size,
                              hipStream_t stream) {
    const float* x = (const float*)d_in[0];   // (4096, 256)
    const float* W = (const float*)d_in[1];   // (4, 512)
    // d_in[2] = b is unused: it cancels in the softmax.
    float* u_part = (float*)d_ws;                       // NB*HH*FDIM = 128K floats
    float* z_part = u_part + (size_t)NB * HH * FDIM;    // NB*HH = 512 floats
    float* out = (float*)d_out;

    void* args[] = { (void*)&x, (void*)&W, (void*)&u_part, (void*)&z_part, (void*)&out };
    hipLaunchCooperativeKernel(reinterpret_cast<void*>(k_fused),
                               dim3(NB), dim3(256), args, 0, stream);
}

// Round 3
// 65.022 us; speedup vs baseline: 1.6803x; 1.6803x over previous
//
#include <hip/hip_runtime.h>

// Problem: N=4096 rows, F=256 features, H=4 heads.
// Softmax identity: softmax_j(s_i[i,h] + s_j[j,h] + b[h]) == softmax_j(s_j[j,h])
// => attention weights independent of i; output is ONE length-F vector broadcast
// to all N rows:
//   v[f] = (1/H) * sum_h ( sum_j exp(s_j[j,h]) * x[j,f] ) / ( sum_j exp(s_j[j,h]) )
//   out[i,f] = leaky_relu(v[f], 0.2)
//
// Round 3: back to 2 plain dispatches (cooperative launch cost +38us in r2).
// k1: 256 blocks x 16 rows -> all 256 CUs busy (r1 used 128).
// k2: column-sliced reduce -> each block reads only its 16-col slice of the
//     partials (float4-vectorized), 16 MiB aggregate L2 traffic vs 64 MiB in r1,
//     and output writes spread over 256 CUs.

#define NROWS 4096
#define FDIM  256
#define HH    4

#define RPB   16              // rows per k1 block
#define NB1   (NROWS / RPB)   // 256 k1 blocks
#define PADF  260             // padded LDS row stride (floats): 16B-aligned, 4-bank shift/row

#define NCS   16              // k2 column slices
#define CSW   (FDIM / NCS)    // 16 cols per slice
#define NRR   16              // k2 row ranges
#define RPB2  (NROWS / NRR)   // 256 rows per k2 block

// ws layout: u_part[NB1][HH][FDIM] (1 MiB), then z_part[NB1][HH] (4 KB).

__global__ __launch_bounds__(256) void k1_part(const float* __restrict__ x,
                                               const float* __restrict__ W,
                                               float* __restrict__ u_part,
                                               float* __restrict__ z_part) {
    __shared__ __align__(16) float x_lds[RPB * PADF];   // 16.6 KB
    __shared__ __align__(16) float w_lds[HH * PADF];    // 4.2 KB
    __shared__ __align__(16) float e_lds[RPB * HH];

    const int t = threadIdx.x;
    const int b = blockIdx.x;
    const int row0 = b * RPB;

    // Stage W2 (= W[:, F:2F], row stride 2F = 128 float4) as [h][c], padded.
    {
        int h = t >> 6, c4 = t & 63;
        float4 wv = ((const float4*)W)[(size_t)h * 128 + 64 + c4];
        *(float4*)&w_lds[h * PADF + c4 * 4] = wv;
    }
    // Stage 16 x-rows: 1024 float4 -> 4 per thread, coalesced.
    for (int i = t; i < RPB * 64; i += 256) {
        int r = i >> 6, c4 = i & 63;
        float4 v = ((const float4*)x)[(size_t)(row0 + r) * 64 + c4];
        *(float4*)&x_lds[r * PADF + c4 * 4] = v;
    }
    __syncthreads();

    // Scores: thread -> (row r, head h, quarter q); 64-feature quarter-dot via
    // float4 LDS reads (index rotated by q to avoid 4-way bank aliasing),
    // then 2-step shfl_xor reduce over q.
    {
        int r = t >> 4, h = (t >> 2) & 3, q = t & 3;
        const float4* xr = (const float4*)&x_lds[r * PADF];
        const float4* wr = (const float4*)&w_lds[h * PADF];
        float acc = 0.f;
        #pragma unroll
        for (int i = 0; i < 16; ++i) {
            int idx = q * 16 + ((i + q * 4) & 15);
            float4 a = xr[idx];
            float4 w = wr[idx];
            acc = fmaf(a.x, w.x, acc); acc = fmaf(a.y, w.y, acc);
            acc = fmaf(a.z, w.z, acc); acc = fmaf(a.w, w.w, acc);
        }
        acc += __shfl_xor(acc, 1);
        acc += __shfl_xor(acc, 2);
        if (q == 0) e_lds[r * 4 + h] = __expf(acc);  // |s| < ~3: no max-shift needed
    }
    __syncthreads();

    // Per-block softmax-denominator partials.
    if (t < HH) {
        float z = 0.f;
        #pragma unroll
        for (int r = 0; r < RPB; ++r) z += e_lds[r * 4 + t];
        z_part[b * HH + t] = z;
    }

    // Per-block partial of u[h][f] = sum_j e[h,j]*x[j,f];  f = t.
    {
        float a0 = 0.f, a1 = 0.f, a2 = 0.f, a3 = 0.f;
        #pragma unroll
        for (int r = 0; r < RPB; ++r) {
            float xv = x_lds[r * PADF + t];
            float4 e4 = *(const float4*)&e_lds[r * 4];   // same addr: broadcast
            a0 = fmaf(e4.x, xv, a0);
            a1 = fmaf(e4.y, xv, a1);
            a2 = fmaf(e4.z, xv, a2);
            a3 = fmaf(e4.w, xv, a3);
        }
        float* up = u_part + (size_t)b * (HH * FDIM);
        up[0 * FDIM + t] = a0;
        up[1 * FDIM + t] = a1;
        up[2 * FDIM + t] = a2;
        up[3 * FDIM + t] = a3;
    }
}

// K2: block (cs, rr) owns cols [cs*16, cs*16+16) x rows [rr*256, rr*256+256).
// Reduces only its 16-col slice of u_part (float4 loads), then broadcast-writes.
__global__ __launch_bounds__(256) void k2_out(const float* __restrict__ u_part,
                                              const float* __restrict__ z_part,
                                              float* __restrict__ out) {
    __shared__ __align__(16) float red[16][HH][CSW];  // [pb-seg][h][col], 4 KB
    __shared__ float red2[HH][CSW];
    __shared__ float zq[16][HH];
    __shared__ float zf[HH];
    __shared__ __align__(16) float v_lds[CSW];

    const int t = threadIdx.x;
    const int cs = blockIdx.x & (NCS - 1);
    const int rr = blockIdx.x >> 4;

    // z partials: 64 threads, each sums 16 pb for one head.
    if (t < 64) {
        int h = t & 3, seg = t >> 2;
        float z = 0.f;
        #pragma unroll 4
        for (int pb = seg * 16; pb < seg * 16 + 16; ++pb)
            z += z_part[pb * HH + h];
        zq[seg][h] = z;
    }

    // u-slice reduce: thread -> (f4-col f4c, head h, pb-seg of 16).
    // Per (pb,h): 16 consecutive floats = one 64B line. 16 float4 loads/thread.
    {
        int f4c = t & 3, h = (t >> 2) & 3, seg = t >> 4;
        const float4* base = (const float4*)u_part + (size_t)h * (FDIM / 4) + cs * 4 + f4c;
        float4 a = {0.f, 0.f, 0.f, 0.f};
        #pragma unroll 4
        for (int pb = seg * 16; pb < seg * 16 + 16; ++pb) {
            float4 u4 = base[(size_t)pb * (HH * FDIM / 4)];
            a.x += u4.x; a.y += u4.y; a.z += u4.z; a.w += u4.w;
        }
        *(float4*)&red[seg][h][f4c * 4] = a;
    }
    __syncthreads();
    if (t < HH) {
        float z = 0.f;
        #pragma unroll
        for (int s = 0; s < 16; ++s) z += zq[s][t];
        zf[t] = z;
    }
    __syncthreads();
    // Combine pb-segs: thread -> (h, col); 16 adds, then /z.
    if (t < 64) {
        int h = t >> 4, col = t & 15;
        float a = 0.f;
        #pragma unroll
        for (int s = 0; s < 16; ++s) a += red[s][h][col];
        red2[h][col] = a / zf[h];
    }
    __syncthreads();
    if (t < CSW) {
        float v = 0.25f * (red2[0][t] + red2[1][t] + red2[2][t] + red2[3][t]);
        v_lds[t] = v > 0.f ? v : 0.2f * v;
    }
    __syncthreads();

    // Write 256 rows x 16 cols: thread -> (f4-col, row); 4 passes of 64 rows.
    // Each row's slice = 64B contiguous (full line).
    const int f4c = t & 3;
    const int rbase = rr * RPB2;
    float4 v4 = *(const float4*)&v_lds[f4c * 4];
    float4* out4 = (float4*)out;
    #pragma unroll
    for (int p = 0; p < 4; ++p) {
        int row = rbase + p * 64 + (t >> 2);
        out4[(size_t)row * (FDIM / 4) + cs * 4 + f4c] = v4;
    }
}

extern "C" void kernel_launch(void* const* d_in, const int* in_sizes, int n_in,
                              void* d_out, int out_size, void* d_ws, size_t ws_size,
                              hipStream_t stream) {
    const float* x = (const float*)d_in[0];   // (4096, 256)
    const float* W = (const float*)d_in[1];   // (4, 512)
    // d_in[2] = b is unused: it cancels in the softmax.
    float* u_part = (float*)d_ws;                       // NB1*HH*FDIM = 256K floats (1 MiB)
    float* z_part = u_part + (size_t)NB1 * HH * FDIM;   // NB1*HH = 1K floats
    float* out = (float*)d_out;

    k1_part<<<NB1, 256, 0, stream>>>(x, W, u_part, z_part);
    k2_out<<<NCS * NRR, 256, 0, stream>>>(u_part, z_part, out);
}